// Round 1
// baseline (35906.088 us; speedup 1.0000x reference)
//
#include <hip/hip_runtime.h>

#define HID 64
#define IMH 64
#define IMW 64
#define HWSZ 4096
#define BATCH 16
#define TSTEPS 16

__device__ __forceinline__ float sigmoidf_(float x) {
    return 1.0f / (1.0f + __expf(-x));
}
__device__ __forceinline__ float tanhf_(float x) {
    // tanh(x) = 1 - 2/(1+e^{2x}); exact at +/-inf, ~2ulp via __expf
    return 1.0f - 2.0f / (1.0f + __expf(2.0f * x));
}

// repack w [256][CIN][3][3] -> wr [CIN][9][256] so weight reads are uniform+contiguous
__global__ void repack_kernel(const float* __restrict__ w, float* __restrict__ wr, int cin) {
    int n = 256 * cin * 9;
    for (int idx = blockIdx.x * blockDim.x + threadIdx.x; idx < n;
         idx += gridDim.x * blockDim.x) {
        int out = idx / (cin * 9);
        int rem = idx - out * (cin * 9);
        int ci  = rem / 9;
        int tap = rem - ci * 9;
        wr[(ci * 9 + tap) * 256 + out] = w[idx];
    }
}

// Fused: gates = conv3x3(concat(xin, hprev)) ; LSTM pointwise update.
// One pixel per thread, 16x16 tile per block. hid processed in 4 groups of 16.
// Input tile (18x18 halo) staged in LDS in chunks of 32 channels.
template<int CIN, int XIN>
__global__ __launch_bounds__(256) void lstm_step_kernel(
    const float* __restrict__ xin, long xbs,     // extra-channel input, batch stride
    const float* __restrict__ hprev,             // [B][HID][H][W]
    float* __restrict__ hnew,                    // [B][HID][H][W]
    float* __restrict__ c,                       // in-place [B][HID][H][W]
    const float* __restrict__ wr,                // [CIN][9][256]
    const float* __restrict__ bias)              // [256] (i,f,o,g × 64)
{
    constexpr int CHUNK = 32;
    __shared__ float lds[CHUNK * 324];           // 32 ch × 18×18 tile = 41.5 KB
    const int tid = threadIdx.x;
    const int tx = tid & 15, ty = tid >> 4;
    const int bx = blockIdx.x * 16, by = blockIdx.y * 16;
    const int b  = blockIdx.z;
    const int px = bx + tx, py = by + ty;

    for (int hg = 0; hg < 4; ++hg) {
        float acc[4][16];
        #pragma unroll
        for (int g = 0; g < 4; ++g)
            #pragma unroll
            for (int k = 0; k < 16; ++k) acc[g][k] = 0.f;

        for (int c0 = 0; c0 < CIN; c0 += CHUNK) {
            const int cn = (CIN - c0 < CHUNK) ? (CIN - c0) : CHUNK;
            __syncthreads();
            // cooperative stage of cn channels of the 18x18 halo tile
            for (int e = tid; e < cn * 324; e += 256) {
                int ch  = e / 324;
                int rem = e - ch * 324;
                int r   = rem / 18;
                int cc  = rem - r * 18;
                int gy = by + r - 1, gx = bx + cc - 1;
                float v = 0.f;
                if (gy >= 0 && gy < IMH && gx >= 0 && gx < IMW) {
                    int vc = c0 + ch;
                    if (vc < XIN)
                        v = xin[(long)b * xbs + (long)vc * HWSZ + gy * IMW + gx];
                    else
                        v = hprev[((long)(b * HID + (vc - XIN))) * HWSZ + gy * IMW + gx];
                }
                lds[e] = v;
            }
            __syncthreads();
            for (int ch = 0; ch < cn; ++ch) {
                const float* lrow = &lds[ch * 324 + ty * 18 + tx];
                const float* wrow = &wr[((long)(c0 + ch)) * (9 * 256) + hg * 16];
                #pragma unroll
                for (int tap = 0; tap < 9; ++tap) {
                    const int dy = tap / 3, dx = tap - dy * 3;
                    float v = lrow[dy * 18 + dx];
                    const float* wt = wrow + tap * 256;   // uniform address -> s_load
                    #pragma unroll
                    for (int g = 0; g < 4; ++g) {
                        #pragma unroll
                        for (int k = 0; k < 16; ++k)
                            acc[g][k] = fmaf(v, wt[g * 64 + k], acc[g][k]);
                    }
                }
            }
        }
        // LSTM pointwise update for hids hg*16 .. hg*16+15
        #pragma unroll
        for (int k = 0; k < 16; ++k) {
            int h = hg * 16 + k;
            float zi = acc[0][k] + bias[h];
            float zf = acc[1][k] + bias[64 + h];
            float zo = acc[2][k] + bias[128 + h];
            float zg = acc[3][k] + bias[192 + h];
            float si = sigmoidf_(zi);
            float sf = sigmoidf_(zf);
            float so = sigmoidf_(zo);
            float tg = tanhf_(zg);
            long idx = ((long)(b * HID + h)) * HWSZ + py * IMW + px;
            float cv = c[idx];
            float cnew = fmaf(sf, cv, si * tg);
            c[idx] = cnew;
            hnew[idx] = so * tanhf_(cnew);
        }
    }
}

__global__ void head_kernel(const float* __restrict__ h1,
                            const float* __restrict__ wh,
                            const float* __restrict__ bh,
                            float* __restrict__ out) {
    int n = blockIdx.x * blockDim.x + threadIdx.x;   // 0..65535
    int b = n >> 12;
    int p = n & 4095;
    float s = bh[0];
    #pragma unroll 8
    for (int h = 0; h < HID; ++h)
        s = fmaf(h1[((long)(b * HID + h)) * HWSZ + p], wh[h], s);
    out[n] = fmaxf(s, 0.f);
}

extern "C" void kernel_launch(void* const* d_in, const int* in_sizes, int n_in,
                              void* d_out, int out_size, void* d_ws, size_t ws_size,
                              hipStream_t stream) {
    const float* x  = (const float*)d_in[0];
    const float* w0 = (const float*)d_in[1];
    const float* b0 = (const float*)d_in[2];
    const float* w1 = (const float*)d_in[3];
    const float* b1 = (const float*)d_in[4];
    const float* wh = (const float*)d_in[5];
    const float* bh = (const float*)d_in[6];
    float* out = (float*)d_out;

    const size_t BUF = (size_t)BATCH * HID * HWSZ;   // 4,194,304 floats (16 MB)
    float* ws  = (float*)d_ws;
    float* h0a = ws;                // zero-init
    float* c0  = ws + BUF;          // zero-init
    float* h1a = ws + 2 * BUF;      // zero-init
    float* c1  = ws + 3 * BUF;      // zero-init
    float* h0b = ws + 4 * BUF;
    float* h1b = ws + 5 * BUF;
    float* wr0 = ws + 6 * BUF;              // 65*9*256  = 149,760 floats
    float* wr1 = wr0 + (size_t)65 * 9 * 256; // 128*9*256 = 294,912 floats

    hipMemsetAsync(d_ws, 0, 4 * BUF * sizeof(float), stream);
    repack_kernel<<<585, 256, 0, stream>>>(w0, wr0, 65);
    repack_kernel<<<1152, 256, 0, stream>>>(w1, wr1, 128);

    float* h0buf[2] = {h0a, h0b};
    float* h1buf[2] = {h1a, h1b};
    dim3 grid(4, 4, BATCH), block(256);
    for (int t = 0; t < TSTEPS; ++t) {
        int cur = t & 1, nxt = cur ^ 1;
        lstm_step_kernel<65, 1><<<grid, block, 0, stream>>>(
            x + (long)t * HWSZ, (long)TSTEPS * HWSZ,
            h0buf[cur], h0buf[nxt], c0, wr0, b0);
        lstm_step_kernel<128, 64><<<grid, block, 0, stream>>>(
            h0buf[nxt], (long)HID * HWSZ,
            h1buf[cur], h1buf[nxt], c1, wr1, b1);
    }
    // t=15 wrote h1buf[0]
    head_kernel<<<256, 256, 0, stream>>>(h1buf[0], wh, bh, out);
}

// Round 2
// 11836.121 us; speedup vs baseline: 3.0336x; 3.0336x over previous
//
#include <hip/hip_runtime.h>

#define HID 64
#define IMH 64
#define IMW 64
#define HWSZ 4096
#define BATCH 16
#define TSTEPS 16

__device__ __forceinline__ float sigmoidf_(float x) {
    return 1.0f / (1.0f + __expf(-x));
}
__device__ __forceinline__ float tanhf_(float x) {
    return 1.0f - 2.0f / (1.0f + __expf(2.0f * x));
}

// repack w [256][CIN][3][3] -> wr [CIN][9][256] so weight reads are uniform+contiguous
__global__ void repack_kernel(const float* __restrict__ w, float* __restrict__ wr, int cin) {
    int n = 256 * cin * 9;
    for (int idx = blockIdx.x * blockDim.x + threadIdx.x; idx < n;
         idx += gridDim.x * blockDim.x) {
        int out = idx / (cin * 9);
        int rem = idx - out * (cin * 9);
        int ci  = rem / 9;
        int tap = rem - ci * 9;
        wr[(ci * 9 + tap) * 256 + out] = w[idx];
    }
}

// Fused conv3x3(concat(xin,hprev)) + LSTM pointwise update.
// Tile: 64 wide (full row) x 4 tall; one pixel/thread; block computes 16 hids
// (hg = blockIdx.y) x 4 gates = 64 fp32 accumulators/thread (kept in VGPRs via
// __launch_bounds__(256,2) -> 256-VGPR cap).
// Input staged in LDS in 16-channel chunks, 6x66 halo rows (2-way bank alias only).
template<int CIN, int XIN>
__global__ __launch_bounds__(256, 2) void lstm_step_kernel(
    const float* __restrict__ xin, long xbs,     // extra-channel input, batch stride
    const float* __restrict__ hprev,             // [B][HID][H][W]
    float* __restrict__ hnew,                    // [B][HID][H][W]
    float* __restrict__ c,                       // in-place [B][HID][H][W]
    const float* __restrict__ wr,                // [CIN][9][256]
    const float* __restrict__ bias)              // [256] (i,f,o,g x 64)
{
    constexpr int CHUNK = 16;
    __shared__ float lds[CHUNK * 396];           // 16 ch x 6x66 = 25.3 KB
    const int tid = threadIdx.x;
    const int col = tid & 63;                    // px (full row -> coalesced)
    const int row = tid >> 6;                    // 0..3
    const int by  = blockIdx.x * 4;              // row-tile origin
    const int hg  = blockIdx.y;                  // hid group 0..3
    const int b   = blockIdx.z;
    const int py  = by + row, px = col;

    float acc[4][16];
    #pragma unroll
    for (int g = 0; g < 4; ++g)
        #pragma unroll
        for (int k = 0; k < 16; ++k) acc[g][k] = 0.f;

    for (int c0 = 0; c0 < CIN; c0 += CHUNK) {
        const int cn = (CIN - c0 < CHUNK) ? (CIN - c0) : CHUNK;
        __syncthreads();
        // stage cn channels of the 6x66 halo tile
        for (int e = tid; e < cn * 396; e += 256) {
            int ch  = e / 396;
            int rem = e - ch * 396;
            int r   = rem / 66;
            int cc  = rem - r * 66;
            int gy = by + r - 1, gx = cc - 1;
            float v = 0.f;
            if (gy >= 0 && gy < IMH && gx >= 0 && gx < IMW) {
                int vc = c0 + ch;
                if (vc < XIN)
                    v = xin[(long)b * xbs + (long)vc * HWSZ + gy * IMW + gx];
                else
                    v = hprev[((long)(b * HID + (vc - XIN))) * HWSZ + gy * IMW + gx];
            }
            lds[e] = v;
        }
        __syncthreads();
        for (int ch = 0; ch < cn; ++ch) {
            float vv[9];
            #pragma unroll
            for (int dy = 0; dy < 3; ++dy)
                #pragma unroll
                for (int dx = 0; dx < 3; ++dx)
                    vv[dy * 3 + dx] = lds[ch * 396 + (row + dy) * 66 + col + dx];
            const float* wrow = &wr[((long)(c0 + ch)) * (9 * 256) + hg * 16];
            #pragma unroll
            for (int tap = 0; tap < 9; ++tap) {
                const float v = vv[tap];
                const float* wt = wrow + tap * 256;   // uniform -> scalar loads
                #pragma unroll
                for (int g = 0; g < 4; ++g) {
                    #pragma unroll
                    for (int k = 0; k < 16; ++k)
                        acc[g][k] = fmaf(v, wt[g * 64 + k], acc[g][k]);
                }
            }
        }
    }

    // LSTM pointwise update for hids hg*16 .. hg*16+15
    #pragma unroll
    for (int k = 0; k < 16; ++k) {
        int h = hg * 16 + k;
        float zi = acc[0][k] + bias[h];
        float zf = acc[1][k] + bias[64 + h];
        float zo = acc[2][k] + bias[128 + h];
        float zg = acc[3][k] + bias[192 + h];
        float si = sigmoidf_(zi);
        float sf = sigmoidf_(zf);
        float so = sigmoidf_(zo);
        float tg = tanhf_(zg);
        long idx = ((long)(b * HID + h)) * HWSZ + py * IMW + px;
        float cv = c[idx];
        float cnew = fmaf(sf, cv, si * tg);
        c[idx] = cnew;
        hnew[idx] = so * tanhf_(cnew);
    }
}

__global__ void head_kernel(const float* __restrict__ h1,
                            const float* __restrict__ wh,
                            const float* __restrict__ bh,
                            float* __restrict__ out) {
    int n = blockIdx.x * blockDim.x + threadIdx.x;   // 0..65535
    int b = n >> 12;
    int p = n & 4095;
    float s = bh[0];
    #pragma unroll 8
    for (int h = 0; h < HID; ++h)
        s = fmaf(h1[((long)(b * HID + h)) * HWSZ + p], wh[h], s);
    out[n] = fmaxf(s, 0.f);
}

extern "C" void kernel_launch(void* const* d_in, const int* in_sizes, int n_in,
                              void* d_out, int out_size, void* d_ws, size_t ws_size,
                              hipStream_t stream) {
    const float* x  = (const float*)d_in[0];
    const float* w0 = (const float*)d_in[1];
    const float* b0 = (const float*)d_in[2];
    const float* w1 = (const float*)d_in[3];
    const float* b1 = (const float*)d_in[4];
    const float* wh = (const float*)d_in[5];
    const float* bh = (const float*)d_in[6];
    float* out = (float*)d_out;

    const size_t BUF = (size_t)BATCH * HID * HWSZ;   // 4,194,304 floats (16 MB)
    float* ws  = (float*)d_ws;
    float* h0a = ws;                // zero-init
    float* c0  = ws + BUF;          // zero-init
    float* h1a = ws + 2 * BUF;      // zero-init
    float* c1  = ws + 3 * BUF;      // zero-init
    float* h0b = ws + 4 * BUF;
    float* h1b = ws + 5 * BUF;
    float* wr0 = ws + 6 * BUF;               // 65*9*256  = 149,760 floats
    float* wr1 = wr0 + (size_t)65 * 9 * 256; // 128*9*256 = 294,912 floats

    hipMemsetAsync(d_ws, 0, 4 * BUF * sizeof(float), stream);
    repack_kernel<<<585, 256, 0, stream>>>(w0, wr0, 65);
    repack_kernel<<<1152, 256, 0, stream>>>(w1, wr1, 128);

    float* h0buf[2] = {h0a, h0b};
    float* h1buf[2] = {h1a, h1b};
    dim3 grid(16, 4, BATCH), block(256);     // 1024 blocks = 4/CU
    for (int t = 0; t < TSTEPS; ++t) {
        int cur = t & 1, nxt = cur ^ 1;
        lstm_step_kernel<65, 1><<<grid, block, 0, stream>>>(
            x + (long)t * HWSZ, (long)TSTEPS * HWSZ,
            h0buf[cur], h0buf[nxt], c0, wr0, b0);
        lstm_step_kernel<128, 64><<<grid, block, 0, stream>>>(
            h0buf[nxt], (long)HID * HWSZ,
            h1buf[cur], h1buf[nxt], c1, wr1, b1);
    }
    // t=15 wrote h1buf[0]
    head_kernel<<<256, 256, 0, stream>>>(h1buf[0], wh, bh, out);
}

// Round 3
// 2041.622 us; speedup vs baseline: 17.5870x; 5.7974x over previous
//
#include <hip/hip_runtime.h>

#define IMH 64
#define IMW 64
#define HWSZ 4096
#define BATCH 16
#define TSTEPS 16

typedef _Float16 half8 __attribute__((ext_vector_type(8)));
typedef float floatx4 __attribute__((ext_vector_type(4)));

__device__ __forceinline__ float sigmoidf_(float x) { return 1.f / (1.f + __expf(-x)); }
__device__ __forceinline__ float tanhf_(float x) { return 1.f - 2.f / (1.f + __expf(2.f * x)); }

__device__ __forceinline__ void gld_lds16(const void* g, void* l) {
    __builtin_amdgcn_global_load_lds(
        (const __attribute__((address_space(1))) unsigned int*)g,
        (__attribute__((address_space(3))) unsigned int*)l, 16, 0, 0);
}

// repack fp32 w [256][CIN][3][3] -> f16 wr [chunk][tap][256][40]
// slot<32: ch = chunk*32+slot (zero-padded past CIN); slots 32..39 are LDS-bank pad (zero)
__global__ void repack_f16_kernel(const float* __restrict__ w, _Float16* __restrict__ wr,
                                  int nchunk, int cin) {
    int total = nchunk * 9 * 256 * 40;
    for (int idx = blockIdx.x * blockDim.x + threadIdx.x; idx < total;
         idx += gridDim.x * blockDim.x) {
        int slot = idx % 40;
        int t = idx / 40;
        int out = t % 256; t /= 256;
        int tap = t % 9;
        int chunk = t / 9;
        int ch = chunk * 32 + slot;
        float v = 0.f;
        if (slot < 32 && ch < cin) v = w[(out * cin + ch) * 9 + tap];
        wr[idx] = (_Float16)v;
    }
}

// Fused conv3x3(concat(xin,hprev)) -> 4 gates -> LSTM update, f16 MFMA implicit GEMM.
// Block: 512 thr (8 waves), covers 2 image rows x 64 cols (N=128 px), M=256 outs.
// Wave wv: hid-group hg=wv&3 (m-tiles at g*64+hg*16, g=0..3 gates), row p=wv>>2.
// K-loop: chunks of 32 channels x 9 taps. Act tile in LDS [4 rows][66 cols][40 f16-slots]
// (transposed for b128 B-frag reads). Weights dbuf in LDS, global_load_lds prefetch.
template<int NCHUNK, int CIN, int XIN>
__global__ __launch_bounds__(512, 4) void lstm_mfma_kernel(
    const float* __restrict__ xin, int xbs,      // first XIN channels, batch stride
    const float* __restrict__ hprev,             // [B][64][H][W] (channels XIN..)
    float* __restrict__ hnew,                    // [B][64][H][W]
    float* __restrict__ cstate,                  // in-place [B][64][H][W]
    const _Float16* __restrict__ wr,             // [NCHUNK][9][256][40]
    const float* __restrict__ bias)              // [256]
{
    __shared__ _Float16 wlds[2][256 * 40];       // 2 x 20 KB
    __shared__ _Float16 actlds[4 * 66 * 40];     // 21 KB

    const int tid = threadIdx.x;
    const int lane = tid & 63;
    const int n = lane & 15, q = lane >> 4;
    const int wv = tid >> 6;
    const int hg = wv & 3;
    const int p = wv >> 2;
    const int rb = blockIdx.x;                   // row-pair 0..31
    const int b = blockIdx.y;
    const int by0 = rb * 2 - 1;

    floatx4 acc[4][4];
    #pragma unroll
    for (int g = 0; g < 4; ++g)
        #pragma unroll
        for (int i = 0; i < 4; ++i) acc[g][i] = (floatx4){0.f, 0.f, 0.f, 0.f};

    auto issue_w = [&](int gt) {
        const _Float16* src = wr + (size_t)gt * 10240;
        _Float16* dst = wlds[gt & 1];
        #pragma unroll
        for (int i = 0; i < 2; ++i)
            gld_lds16(src + (size_t)(tid + i * 512) * 8, dst + (tid + i * 512) * 8);
        if (tid < 256)
            gld_lds16(src + (size_t)(tid + 1024) * 8, dst + (tid + 1024) * 8);
    };

    issue_w(0);

    for (int chunk = 0; chunk < NCHUNK; ++chunk) {
        __syncthreads();   // act buffer free (prev chunk's MFMA done)
        // stage act tile: 4 rows x 66 cols x 32 ch (f16, transposed)
        for (int e = tid; e < 1056; e += 512) {
            int rg = e / 66;
            int cs = e - rg * 66;
            int r = rg >> 2, g = rg & 3;
            int gy = by0 + r;
            int gx = cs - 1;
            bool inb = (gy >= 0) && (gy < IMH) && (gx >= 0) && (gx < IMW);
            int ch0 = chunk * 32 + g * 8;
            half8 hv;
            #pragma unroll
            for (int j = 0; j < 8; ++j) {
                int vc = ch0 + j;
                float xv = 0.f;
                if (inb && vc < CIN)
                    xv = (vc < XIN)
                       ? xin[(size_t)b * xbs + (size_t)vc * HWSZ + gy * IMW + gx]
                       : hprev[(size_t)(b * 64 + (vc - XIN)) * HWSZ + gy * IMW + gx];
                hv[j] = (_Float16)xv;
            }
            *(half8*)&actlds[(r * 66 + cs) * 40 + g * 8] = hv;
        }

        #pragma unroll
        for (int tap = 0; tap < 9; ++tap) {
            const int gt = chunk * 9 + tap;
            __syncthreads();   // drains vmcnt -> wlds[gt&1] ready; act visible; other buf free
            if (gt + 1 < NCHUNK * 9) issue_w(gt + 1);
            const _Float16* wb = wlds[gt & 1];
            const int dy = tap / 3, dx = tap % 3;
            half8 bfr[4];
            #pragma unroll
            for (int ni = 0; ni < 4; ++ni)
                bfr[ni] = *(const half8*)&actlds[((p + dy) * 66 + 16 * ni + n + dx) * 40 + q * 8];
            #pragma unroll
            for (int g = 0; g < 4; ++g) {
                half8 afr = *(const half8*)&wb[(g * 64 + hg * 16 + n) * 40 + q * 8];
                #pragma unroll
                for (int ni = 0; ni < 4; ++ni)
                    acc[g][ni] = __builtin_amdgcn_mfma_f32_16x16x32_f16(
                        afr, bfr[ni], acc[g][ni], 0, 0, 0);
            }
        }
    }

    // LSTM pointwise update, all in-register:
    // lane holds gates for h = hg*16 + q*4 + r, px col = 16*ni + n, row y = 2*rb + p
    const int y = rb * 2 + p;
    const int hb = hg * 16 + q * 4;
    floatx4 bi = *(const floatx4*)&bias[hb];
    floatx4 bf = *(const floatx4*)&bias[64 + hb];
    floatx4 bo = *(const floatx4*)&bias[128 + hb];
    floatx4 bg = *(const floatx4*)&bias[192 + hb];
    #pragma unroll
    for (int ni = 0; ni < 4; ++ni) {
        int col = 16 * ni + n;
        #pragma unroll
        for (int r = 0; r < 4; ++r) {
            size_t idx = (size_t)(b * 64 + hb + r) * HWSZ + y * IMW + col;
            float zi = acc[0][ni][r] + bi[r];
            float zf = acc[1][ni][r] + bf[r];
            float zo = acc[2][ni][r] + bo[r];
            float zg = acc[3][ni][r] + bg[r];
            float cv = cstate[idx];
            float cn = fmaf(sigmoidf_(zf), cv, sigmoidf_(zi) * tanhf_(zg));
            cstate[idx] = cn;
            hnew[idx] = sigmoidf_(zo) * tanhf_(cn);
        }
    }
}

__global__ void head_kernel(const float* __restrict__ h1,
                            const float* __restrict__ wh,
                            const float* __restrict__ bh,
                            float* __restrict__ out) {
    int nn = blockIdx.x * blockDim.x + threadIdx.x;  // 0..65535
    int b = nn >> 12;
    int pp = nn & 4095;
    float s = bh[0];
    #pragma unroll 8
    for (int h = 0; h < 64; ++h)
        s = fmaf(h1[(size_t)(b * 64 + h) * HWSZ + pp], wh[h], s);
    out[nn] = fmaxf(s, 0.f);
}

extern "C" void kernel_launch(void* const* d_in, const int* in_sizes, int n_in,
                              void* d_out, int out_size, void* d_ws, size_t ws_size,
                              hipStream_t stream) {
    const float* x  = (const float*)d_in[0];
    const float* w0 = (const float*)d_in[1];
    const float* b0 = (const float*)d_in[2];
    const float* w1 = (const float*)d_in[3];
    const float* b1 = (const float*)d_in[4];
    const float* wh = (const float*)d_in[5];
    const float* bh = (const float*)d_in[6];
    float* out = (float*)d_out;

    const size_t BUF = (size_t)BATCH * 64 * HWSZ;    // 4,194,304 floats (16 MB)
    float* ws  = (float*)d_ws;
    float* h0a = ws;                 // zero-init
    float* c0  = ws + BUF;           // zero-init
    float* h1a = ws + 2 * BUF;       // zero-init
    float* c1  = ws + 3 * BUF;       // zero-init
    float* h0b = ws + 4 * BUF;
    float* h1b = ws + 5 * BUF;
    _Float16* wr0 = (_Float16*)(ws + 6 * BUF);       // 3*9*256*40 = 276,480 halves
    _Float16* wr1 = wr0 + (size_t)3 * 9 * 256 * 40;  // 4*9*256*40 = 368,640 halves

    hipMemsetAsync(d_ws, 0, 4 * BUF * sizeof(float), stream);
    repack_f16_kernel<<<1080, 256, 0, stream>>>(w0, wr0, 3, 65);
    repack_f16_kernel<<<1440, 256, 0, stream>>>(w1, wr1, 4, 128);

    float* h0buf[2] = {h0a, h0b};
    float* h1buf[2] = {h1a, h1b};
    dim3 grid(32, BATCH), block(512);
    for (int t = 0; t < TSTEPS; ++t) {
        int cur = t & 1, nxt = cur ^ 1;
        // layer0: input = [x_t(1), h0(64)]
        lstm_mfma_kernel<3, 65, 1><<<grid, block, 0, stream>>>(
            x + (size_t)t * HWSZ, TSTEPS * HWSZ,
            h0buf[cur], h0buf[nxt], c0, wr0, b0);
        // layer1: input = [h0_new(64), h1(64)]
        lstm_mfma_kernel<4, 128, 64><<<grid, block, 0, stream>>>(
            h0buf[nxt], 64 * HWSZ,
            h1buf[cur], h1buf[nxt], c1, wr1, b1);
    }
    // t=15 wrote h1buf[0]
    head_kernel<<<256, 256, 0, stream>>>(h1buf[0], wh, bh, out);
}